// Round 13
// baseline (32.245 us; speedup 1.0000x reference)
//
#include <hip/hip_runtime.h>
#include <hip/hip_fp16.h>

#define NPART 500000
#define MPART 450000
#define NBXC 1024
#define NBYC 1024
#define NPARTIAL 512            // field blocks
#define NBLK_PART 1954          // ceil(500000/256)

typedef float fvec4 __attribute__((ext_vector_type(4)));

// Tiled field layout: 2x8-cell tiles (2 x-rows x 8 y-cells x 4B = 64B = one
// L2 sector). tile (tx,ty), tx=x>>1, ty=y>>3, tx-major.
// cell index = ((tx*128 + ty)*16) + (x&1)*8 + (y&7)
__device__ __forceinline__ int tidx(int x, int y) {
    return ((((x >> 1) * 128 + (y >> 3)) << 4) + ((x & 1) << 3) + (y & 7));
}

// ---------------------------------------------------------------------------
// Kernel A: velocity field. One thread = one tile-row (row x, cells
// j0..j0+7) -> 32B contiguous store. pot/rho loads are non-temporal (pure
// streaming) so they don't evict the v field from L2.
// ---------------------------------------------------------------------------
__global__ __launch_bounds__(256) void field_kernel(const float* __restrict__ pot,
                                                    const float* __restrict__ rho,
                                                    __half2* __restrict__ v,
                                                    float* __restrict__ partials) {
    const int idx = blockIdx.x * 256 + threadIdx.x;      // 0 .. 131071
    const int x  = idx >> 7;                             // row 0..1023
    const int ty = idx & 127;                            // y-tile 0..127
    const int j0 = ty << 3;                              // col 0,8,..,1016

    const int ip = min(x + 1, NBXC - 1);
    const int im = max(x - 1, 0);
    const float sx = (ip - im == 2) ? 0.5f : 1.0f;

    const fvec4* pc = reinterpret_cast<const fvec4*>(pot + x  * NBYC + j0);
    const fvec4* pu = reinterpret_cast<const fvec4*>(pot + ip * NBYC + j0);
    const fvec4* pd = reinterpret_cast<const fvec4*>(pot + im * NBYC + j0);
    const fvec4* pr = reinterpret_cast<const fvec4*>(rho + x  * NBYC + j0);
    float c[8], u[8], d[8], r[8];
    *reinterpret_cast<fvec4*>(c)     = __builtin_nontemporal_load(pc);
    *reinterpret_cast<fvec4*>(c + 4) = __builtin_nontemporal_load(pc + 1);
    *reinterpret_cast<fvec4*>(u)     = __builtin_nontemporal_load(pu);
    *reinterpret_cast<fvec4*>(u + 4) = __builtin_nontemporal_load(pu + 1);
    *reinterpret_cast<fvec4*>(d)     = __builtin_nontemporal_load(pd);
    *reinterpret_cast<fvec4*>(d + 4) = __builtin_nontemporal_load(pd + 1);
    *reinterpret_cast<fvec4*>(r)     = __builtin_nontemporal_load(pr);
    *reinterpret_cast<fvec4*>(r + 4) = __builtin_nontemporal_load(pr + 1);
    const float cl = __builtin_nontemporal_load(pot + x * NBYC + max(j0 - 1, 0));
    const float cr = __builtin_nontemporal_load(pot + x * NBYC + min(j0 + 8, NBYC - 1));

    float vx[8], vy[8];
    #pragma unroll
    for (int k = 0; k < 8; ++k) vx[k] = -(u[k] - d[k]) * sx;
    vy[0] = (j0 == 0) ? -(c[1] - c[0]) : -(c[1] - cl) * 0.5f;
    #pragma unroll
    for (int k = 1; k < 7; ++k) vy[k] = -(c[k + 1] - c[k - 1]) * 0.5f;
    vy[7] = (j0 + 7 == NBYC - 1) ? -(c[7] - c[6]) : -(cr - c[6]) * 0.5f;

    float st[8];
    #pragma unroll
    for (int k = 0; k < 8; ++k)
        st[k] = __builtin_bit_cast(float, __floats2half2_rn(vx[k], vy[k]));
    // v store stays cached: we WANT the field resident in L2
    fvec4* vp = reinterpret_cast<fvec4*>(v + ((((x >> 1) * 128 + ty) << 4) + ((x & 1) << 3)));
    vp[0] = *reinterpret_cast<fvec4*>(st);
    vp[1] = *reinterpret_cast<fvec4*>(st + 4);

    float e = 0.0f;
    #pragma unroll
    for (int k = 0; k < 8; ++k) e += r[k] * (vx[k] * vx[k] + vy[k] * vy[k]);
    #pragma unroll
    for (int off = 32; off > 0; off >>= 1) e += __shfl_down(e, off, 64);
    __shared__ float smem[4];
    const int lane = threadIdx.x & 63;
    const int wid  = threadIdx.x >> 6;
    if (lane == 0) smem[wid] = e;
    __syncthreads();
    if (threadIdx.x == 0) partials[blockIdx.x] = (smem[0] + smem[1]) + (smem[2] + smem[3]);
}

// ---------------------------------------------------------------------------
// Kernel C: per-particle gradient (blocks 0..1953) + energy reduction
// (block 1954). Identical arithmetic to round 10; particle streams
// (pos/nsx/nsy loads, out stores) are non-temporal so the 4MB field isn't
// evicted from L2 by the ~12MB of streaming traffic.
// ---------------------------------------------------------------------------
__global__ __launch_bounds__(256) void particle_kernel(const float* __restrict__ pos,
                                                       const float* __restrict__ nsx,
                                                       const float* __restrict__ nsy,
                                                       const __half2* __restrict__ v,
                                                       const float* __restrict__ partials,
                                                       float* __restrict__ out) {
    __shared__ float smem[4];

    if (blockIdx.x == NBLK_PART) {      // ---- energy reduction block ----
        const int t = threadIdx.x;
        float e = partials[t] + partials[t + 256];
        #pragma unroll
        for (int off = 32; off > 0; off >>= 1) e += __shfl_down(e, off, 64);
        const int lane = t & 63;
        const int wid  = t >> 6;
        if (lane == 0) smem[wid] = e;
        __syncthreads();
        if (t == 0) out[0] = 0.5f * ((smem[0] + smem[1]) + (smem[2] + smem[3]));
        return;
    }

    const int i = blockIdx.x * 256 + threadIdx.x;
    if (i >= NPART) return;
    if (i >= MPART) {                   // zero pad regions [M:N), [N+M:2N)
        __builtin_nontemporal_store(0.0f, out + 1 + i);
        __builtin_nontemporal_store(0.0f, out + 1 + NPART + i);
        return;
    }

    const float px = __builtin_nontemporal_load(pos + i);
    const float py = __builtin_nontemporal_load(pos + NPART + i);
    const float w  = __builtin_nontemporal_load(nsx + i);
    const float h  = __builtin_nontemporal_load(nsy + i);

    float gpx, gpy;
    const bool large = (w >= 1.0f) || (h >= 1.0f);
    if (!large) {
        int ix = min(max((int)floorf(px), 0), NBXC - 1);
        int iy = min(max((int)floorf(py), 0), NBYC - 1);
        const float wx = fminf(fmaxf(px - (float)ix, 0.0f), 1.0f);
        const float wy = fminf(fmaxf(py - (float)iy, 0.0f), 1.0f);
        const int ix1 = min(ix + 1, NBXC - 1);
        const int iy1 = min(iy + 1, NBYC - 1);
        const float2 f00 = __half22float2(v[tidx(ix,  iy )]);
        const float2 f10 = __half22float2(v[tidx(ix1, iy )]);
        const float2 f01 = __half22float2(v[tidx(ix,  iy1)]);
        const float2 f11 = __half22float2(v[tidx(ix1, iy1)]);
        const float w00 = (1.0f - wx) * (1.0f - wy);
        const float w10 = wx * (1.0f - wy);
        const float w01 = (1.0f - wx) * wy;
        const float w11 = wx * wy;
        gpx = w00 * f00.x + w10 * f10.x + w01 * f01.x + w11 * f11.x;
        gpy = w00 * f00.y + w10 * f10.y + w01 * f01.y + w11 * f11.y;
    } else {
        const float lx = px - 0.5f * w, rx = px + 0.5f * w;
        const float ly = py - 0.5f * h, ry = py + 0.5f * h;
        const int bminx = min(max((int)floorf(lx), 0), NBXC - 1);
        const int bmaxx = min(max((int)floorf(rx), 0), NBXC - 1);
        const int bminy = min(max((int)floorf(ly), 0), NBYC - 1);
        const int bmaxy = min(max((int)floorf(ry), 0), NBYC - 1);
        const int by0 = min(bminy & ~7, NBYC - 16);   // <=2 y-tiles always
        const int ty0 = by0 >> 3;
        const int bx0 = bminx & ~1;                   // 2-aligned x start
        const bool y2 = (bmaxy - by0) >= 8;

        float oy[16];
        #pragma unroll
        for (int k = 0; k < 16; ++k) {
            const int b = by0 + k;
            const float bl = (float)b;
            float ov = fminf(ry, bl + 1.0f) - fmaxf(ly, bl);
            oy[k] = (b <= bmaxy && ov > 0.0f) ? ov : 0.0f;
        }
        float ox[8];
        #pragma unroll
        for (int k = 0; k < 8; ++k) {
            const int b = bx0 + k;
            const float bl = (float)b;
            float ov = fminf(rx, bl + 1.0f) - fmaxf(lx, bl);
            ov = (b <= bmaxx && ov > 0.0f) ? ov : 0.0f;
            ox[k] = ov;
        }

        const fvec4 z = {0.0f, 0.0f, 0.0f, 0.0f};
        float afx = 0.0f, afy = 0.0f;
        #pragma unroll
        for (int p = 0; p < 4; ++p) {
            const float ov0 = ox[2 * p], ov1 = ox[2 * p + 1];
            if (ov0 > 0.0f || ov1 > 0.0f) {     // exec-masked tile-pair
                const fvec4* tp = reinterpret_cast<const fvec4*>(
                    v + (((((bx0 >> 1) + p) * 128 + ty0) << 4)));
                fvec4 A0 = tp[0], A1 = tp[1], B0 = tp[2], B1 = tp[3];
                fvec4 A2 = z, A3 = z, B2 = z, B3 = z;
                if (y2) { A2 = tp[4]; A3 = tp[5]; B2 = tp[6]; B3 = tp[7]; }
                float sxa = 0.0f, sya = 0.0f, sxb = 0.0f, syb = 0.0f;
                const float* a0 = reinterpret_cast<const float*>(&A0);
                const float* a1 = reinterpret_cast<const float*>(&A1);
                const float* a2 = reinterpret_cast<const float*>(&A2);
                const float* a3 = reinterpret_cast<const float*>(&A3);
                const float* b0 = reinterpret_cast<const float*>(&B0);
                const float* b1 = reinterpret_cast<const float*>(&B1);
                const float* b2 = reinterpret_cast<const float*>(&B2);
                const float* b3 = reinterpret_cast<const float*>(&B3);
                #pragma unroll
                for (int e = 0; e < 4; ++e) {
                    float2 f;
                    f = __half22float2(__builtin_bit_cast(__half2, a0[e]));
                    sxa += f.x * oy[e];      sya += f.y * oy[e];
                    f = __half22float2(__builtin_bit_cast(__half2, a1[e]));
                    sxa += f.x * oy[4 + e];  sya += f.y * oy[4 + e];
                    f = __half22float2(__builtin_bit_cast(__half2, a2[e]));
                    sxa += f.x * oy[8 + e];  sya += f.y * oy[8 + e];
                    f = __half22float2(__builtin_bit_cast(__half2, a3[e]));
                    sxa += f.x * oy[12 + e]; sya += f.y * oy[12 + e];
                    f = __half22float2(__builtin_bit_cast(__half2, b0[e]));
                    sxb += f.x * oy[e];      syb += f.y * oy[e];
                    f = __half22float2(__builtin_bit_cast(__half2, b1[e]));
                    sxb += f.x * oy[4 + e];  syb += f.y * oy[4 + e];
                    f = __half22float2(__builtin_bit_cast(__half2, b2[e]));
                    sxb += f.x * oy[8 + e];  syb += f.y * oy[8 + e];
                    f = __half22float2(__builtin_bit_cast(__half2, b3[e]));
                    sxb += f.x * oy[12 + e]; syb += f.y * oy[12 + e];
                }
                afx += sxa * ov0 + sxb * ov1;
                afy += sya * ov0 + syb * ov1;
            }
        }
        const float inv = 1.0f / fmaxf(w * h, 1e-30f);
        gpx = afx * inv;
        gpy = afy * inv;
    }
    __builtin_nontemporal_store(gpx, out + 1 + i);
    __builtin_nontemporal_store(gpy, out + 1 + NPART + i);
}

extern "C" void kernel_launch(void* const* d_in, const int* in_sizes, int n_in,
                              void* d_out, int out_size, void* d_ws, size_t ws_size,
                              hipStream_t stream) {
    const float* pos = (const float*)d_in[0];
    const float* pot = (const float*)d_in[1];
    const float* rho = (const float*)d_in[2];
    const float* nsx = (const float*)d_in[3];
    const float* nsy = (const float*)d_in[4];
    float* out = (float*)d_out;

    __half2* v      = (__half2*)d_ws;                                     // 4 MB (2x8 tiled)
    float* partials = (float*)((char*)d_ws + (size_t)NBXC * NBYC * sizeof(__half2));

    field_kernel<<<NPARTIAL, 256, 0, stream>>>(pot, rho, v, partials);
    particle_kernel<<<NBLK_PART + 1, 256, 0, stream>>>(pos, nsx, nsy, v, partials, out);
}

// Round 14
// 29.929 us; speedup vs baseline: 1.0774x; 1.0774x over previous
//
#include <hip/hip_runtime.h>
#include <hip/hip_fp16.h>

#define NPART 500000
#define MPART 450000
#define NBXC 1024
#define NBYC 1024
#define NPARTIAL 512            // field blocks
#define NBLK_PART 1954          // ceil(500000/256)

typedef float  fvec4 __attribute__((ext_vector_type(4)));
typedef _Float16 h2  __attribute__((ext_vector_type(2)));

// Planar tiled field layout: one tile = 2 x-rows x 8 y-cells = 64B = one L2
// sector, stored PLANAR: halfs [0..7]=vx row0, [8..15]=vx row1,
// [16..23]=vy row0, [24..31]=vy row1. tile (tx,ty), tx=x>>1, ty=y>>3,
// tx-major so (tx,ty)/(tx,ty+1) are +64B adjacent.
// Same sector geometry/load addresses as round 10; planar so each float4
// feeds v_dot2_f32_f16 directly (4x fewer VALU ops than cvt+FMA).

// ---------------------------------------------------------------------------
// Kernel A: velocity field. One thread = one tile-row (row x, cells
// j0..j0+7) -> two 16B stores (vx plane, vy plane). 512 blocks.
// ---------------------------------------------------------------------------
__global__ __launch_bounds__(256) void field_kernel(const float* __restrict__ pot,
                                                    const float* __restrict__ rho,
                                                    __half* __restrict__ v,
                                                    float* __restrict__ partials) {
    const int idx = blockIdx.x * 256 + threadIdx.x;      // 0 .. 131071
    const int x  = idx >> 7;                             // row 0..1023
    const int ty = idx & 127;                            // y-tile 0..127
    const int j0 = ty << 3;                              // col 0,8,..,1016

    const int ip = min(x + 1, NBXC - 1);
    const int im = max(x - 1, 0);
    const float sx = (ip - im == 2) ? 0.5f : 1.0f;

    const fvec4* pc = reinterpret_cast<const fvec4*>(pot + x  * NBYC + j0);
    const fvec4* pu = reinterpret_cast<const fvec4*>(pot + ip * NBYC + j0);
    const fvec4* pd = reinterpret_cast<const fvec4*>(pot + im * NBYC + j0);
    const fvec4* pr = reinterpret_cast<const fvec4*>(rho + x  * NBYC + j0);
    float c[8], u[8], d[8], r[8];
    *reinterpret_cast<fvec4*>(c)     = pc[0]; *reinterpret_cast<fvec4*>(c + 4) = pc[1];
    *reinterpret_cast<fvec4*>(u)     = pu[0]; *reinterpret_cast<fvec4*>(u + 4) = pu[1];
    *reinterpret_cast<fvec4*>(d)     = pd[0]; *reinterpret_cast<fvec4*>(d + 4) = pd[1];
    *reinterpret_cast<fvec4*>(r)     = pr[0]; *reinterpret_cast<fvec4*>(r + 4) = pr[1];
    const float cl = pot[x * NBYC + max(j0 - 1, 0)];
    const float cr = pot[x * NBYC + min(j0 + 8, NBYC - 1)];

    float vx[8], vy[8];
    #pragma unroll
    for (int k = 0; k < 8; ++k) vx[k] = -(u[k] - d[k]) * sx;
    vy[0] = (j0 == 0) ? -(c[1] - c[0]) : -(c[1] - cl) * 0.5f;
    #pragma unroll
    for (int k = 1; k < 7; ++k) vy[k] = -(c[k + 1] - c[k - 1]) * 0.5f;
    vy[7] = (j0 + 7 == NBYC - 1) ? -(c[7] - c[6]) : -(cr - c[6]) * 0.5f;

    // planar packed stores: half2 = (comp[2k], comp[2k+1]) along y
    float stx[4], sty[4];
    #pragma unroll
    for (int k = 0; k < 4; ++k) {
        stx[k] = __builtin_bit_cast(float, __floats2half2_rn(vx[2 * k], vx[2 * k + 1]));
        sty[k] = __builtin_bit_cast(float, __floats2half2_rn(vy[2 * k], vy[2 * k + 1]));
    }
    __half* tp = v + ((((x >> 1) * 128 + ty) << 5) + ((x & 1) << 3));
    *reinterpret_cast<fvec4*>(tp)      = *reinterpret_cast<fvec4*>(stx);
    *reinterpret_cast<fvec4*>(tp + 16) = *reinterpret_cast<fvec4*>(sty);

    float e = 0.0f;
    #pragma unroll
    for (int k = 0; k < 8; ++k) e += r[k] * (vx[k] * vx[k] + vy[k] * vy[k]);
    #pragma unroll
    for (int off = 32; off > 0; off >>= 1) e += __shfl_down(e, off, 64);
    __shared__ float smem[4];
    const int lane = threadIdx.x & 63;
    const int wid  = threadIdx.x >> 6;
    if (lane == 0) smem[wid] = e;
    __syncthreads();
    if (threadIdx.x == 0) partials[blockIdx.x] = (smem[0] + smem[1]) + (smem[2] + smem[3]);
}

// bilinear tap from planar tiled layout
__device__ __forceinline__ float2 vload(const __half* __restrict__ v, int x, int y) {
    const __half* t = v + ((((x >> 1) * 128 + (y >> 3)) << 5) + ((x & 1) << 3) + (y & 7));
    return make_float2(__half2float(t[0]), __half2float(t[16]));
}

// ---------------------------------------------------------------------------
// Kernel C: per-particle gradient (blocks 0..1953) + energy reduction
// (block 1954). Same gather structure as round 10 (exec-masked tile-pairs,
// <=2 y-tiles); inner math via v_dot2_f32_f16 (f32 accumulate).
// ---------------------------------------------------------------------------
__global__ __launch_bounds__(256) void particle_kernel(const float* __restrict__ pos,
                                                       const float* __restrict__ nsx,
                                                       const float* __restrict__ nsy,
                                                       const __half* __restrict__ v,
                                                       const float* __restrict__ partials,
                                                       float* __restrict__ out) {
    __shared__ float smem[4];

    if (blockIdx.x == NBLK_PART) {      // ---- energy reduction block ----
        const int t = threadIdx.x;
        float e = partials[t] + partials[t + 256];
        #pragma unroll
        for (int off = 32; off > 0; off >>= 1) e += __shfl_down(e, off, 64);
        const int lane = t & 63;
        const int wid  = t >> 6;
        if (lane == 0) smem[wid] = e;
        __syncthreads();
        if (t == 0) out[0] = 0.5f * ((smem[0] + smem[1]) + (smem[2] + smem[3]));
        return;
    }

    const int i = blockIdx.x * 256 + threadIdx.x;
    if (i >= NPART) return;
    if (i >= MPART) {                   // zero pad regions [M:N), [N+M:2N)
        out[1 + i]         = 0.0f;
        out[1 + NPART + i] = 0.0f;
        return;
    }

    const float px = pos[i];
    const float py = pos[NPART + i];
    const float w  = nsx[i];
    const float h  = nsy[i];

    float gpx, gpy;
    const bool large = (w >= 1.0f) || (h >= 1.0f);
    if (!large) {
        int ix = min(max((int)floorf(px), 0), NBXC - 1);
        int iy = min(max((int)floorf(py), 0), NBYC - 1);
        const float wx = fminf(fmaxf(px - (float)ix, 0.0f), 1.0f);
        const float wy = fminf(fmaxf(py - (float)iy, 0.0f), 1.0f);
        const int ix1 = min(ix + 1, NBXC - 1);
        const int iy1 = min(iy + 1, NBYC - 1);
        const float2 f00 = vload(v, ix,  iy );
        const float2 f10 = vload(v, ix1, iy );
        const float2 f01 = vload(v, ix,  iy1);
        const float2 f11 = vload(v, ix1, iy1);
        const float w00 = (1.0f - wx) * (1.0f - wy);
        const float w10 = wx * (1.0f - wy);
        const float w01 = (1.0f - wx) * wy;
        const float w11 = wx * wy;
        gpx = w00 * f00.x + w10 * f10.x + w01 * f01.x + w11 * f11.x;
        gpy = w00 * f00.y + w10 * f10.y + w01 * f01.y + w11 * f11.y;
    } else {
        const float lx = px - 0.5f * w, rx = px + 0.5f * w;
        const float ly = py - 0.5f * h, ry = py + 0.5f * h;
        const int bminx = min(max((int)floorf(lx), 0), NBXC - 1);
        const int bmaxx = min(max((int)floorf(rx), 0), NBXC - 1);
        const int bminy = min(max((int)floorf(ly), 0), NBYC - 1);
        const int bmaxy = min(max((int)floorf(ry), 0), NBYC - 1);
        const int by0 = min(bminy & ~7, NBYC - 16);   // <=2 y-tiles always
        const int ty0 = by0 >> 3;
        const int bx0 = bminx & ~1;                   // 2-aligned x start
        const bool y2 = (bmaxy - by0) >= 8;

        // y-overlap weights as half2 pairs (f16 weights, f32 accumulation)
        h2 hoy[8];
        #pragma unroll
        for (int k = 0; k < 8; ++k) {
            const int b0 = by0 + 2 * k, b1 = b0 + 1;
            float o0 = fminf(ry, (float)b0 + 1.0f) - fmaxf(ly, (float)b0);
            float o1 = fminf(ry, (float)b1 + 1.0f) - fmaxf(ly, (float)b1);
            o0 = (b0 <= bmaxy && o0 > 0.0f) ? o0 : 0.0f;
            o1 = (b1 <= bmaxy && o1 > 0.0f) ? o1 : 0.0f;
            hoy[k] = h2{(_Float16)o0, (_Float16)o1};
        }
        float ox[8];
        #pragma unroll
        for (int k = 0; k < 8; ++k) {
            const int b = bx0 + k;
            const float bl = (float)b;
            float ov = fminf(rx, bl + 1.0f) - fmaxf(lx, bl);
            ox[k] = (b <= bmaxx && ov > 0.0f) ? ov : 0.0f;
        }

        const fvec4 z = {0.0f, 0.0f, 0.0f, 0.0f};
        float afx = 0.0f, afy = 0.0f;
        #pragma unroll
        for (int p = 0; p < 4; ++p) {
            const float ov0 = ox[2 * p], ov1 = ox[2 * p + 1];
            if (ov0 > 0.0f || ov1 > 0.0f) {     // exec-masked tile-pair
                const fvec4* tp = reinterpret_cast<const fvec4*>(
                    v + (((((bx0 >> 1) + p) * 128 + ty0) << 5)));
                // tile0: [0]=vx rowA, [1]=vx rowB, [2]=vy rowA, [3]=vy rowB
                fvec4 XA0 = tp[0], XB0 = tp[1], YA0 = tp[2], YB0 = tp[3];
                fvec4 XA1 = z, XB1 = z, YA1 = z, YB1 = z;
                if (y2) { XA1 = tp[4]; XB1 = tp[5]; YA1 = tp[6]; YB1 = tp[7]; }

                float sxa = 0.0f, sxb = 0.0f, sya = 0.0f, syb = 0.0f;
                #pragma unroll
                for (int e = 0; e < 4; ++e) {
                    sxa = __builtin_amdgcn_fdot2(__builtin_bit_cast(h2, XA0[e]), hoy[e],     sxa, false);
                    sxb = __builtin_amdgcn_fdot2(__builtin_bit_cast(h2, XB0[e]), hoy[e],     sxb, false);
                    sya = __builtin_amdgcn_fdot2(__builtin_bit_cast(h2, YA0[e]), hoy[e],     sya, false);
                    syb = __builtin_amdgcn_fdot2(__builtin_bit_cast(h2, YB0[e]), hoy[e],     syb, false);
                    sxa = __builtin_amdgcn_fdot2(__builtin_bit_cast(h2, XA1[e]), hoy[4 + e], sxa, false);
                    sxb = __builtin_amdgcn_fdot2(__builtin_bit_cast(h2, XB1[e]), hoy[4 + e], sxb, false);
                    sya = __builtin_amdgcn_fdot2(__builtin_bit_cast(h2, YA1[e]), hoy[4 + e], sya, false);
                    syb = __builtin_amdgcn_fdot2(__builtin_bit_cast(h2, YB1[e]), hoy[4 + e], syb, false);
                }
                afx += sxa * ov0 + sxb * ov1;
                afy += sya * ov0 + syb * ov1;
            }
        }
        const float inv = 1.0f / fmaxf(w * h, 1e-30f);
        gpx = afx * inv;
        gpy = afy * inv;
    }
    out[1 + i]         = gpx;
    out[1 + NPART + i] = gpy;
}

extern "C" void kernel_launch(void* const* d_in, const int* in_sizes, int n_in,
                              void* d_out, int out_size, void* d_ws, size_t ws_size,
                              hipStream_t stream) {
    const float* pos = (const float*)d_in[0];
    const float* pot = (const float*)d_in[1];
    const float* rho = (const float*)d_in[2];
    const float* nsx = (const float*)d_in[3];
    const float* nsy = (const float*)d_in[4];
    float* out = (float*)d_out;

    __half* v       = (__half*)d_ws;                                      // 4 MB (planar tiled)
    float* partials = (float*)((char*)d_ws + (size_t)2 * NBXC * NBYC * sizeof(__half));

    field_kernel<<<NPARTIAL, 256, 0, stream>>>(pot, rho, v, partials);
    particle_kernel<<<NBLK_PART + 1, 256, 0, stream>>>(pos, nsx, nsy, v, partials, out);
}